// Round 1
// baseline (1177.878 us; speedup 1.0000x reference)
//
#include <hip/hip_runtime.h>

// ---------------- degree / normalization ----------------

__global__ void deg_init(float* __restrict__ deg, int n) {
  int i = blockIdx.x * blockDim.x + threadIdx.x;
  if (i < n) deg[i] = 1.0f;  // self-loop
}

__global__ void deg_count(const int* __restrict__ dst, float* __restrict__ deg, int E) {
  int i = blockIdx.x * blockDim.x + threadIdx.x;
  int stride = gridDim.x * blockDim.x;
  for (; i < E; i += stride) atomicAdd(&deg[dst[i]], 1.0f);
}

__global__ void deg_to_dinv(float* __restrict__ deg, int n) {
  int i = blockIdx.x * blockDim.x + threadIdx.x;
  if (i < n) deg[i] = rsqrtf(deg[i]);  // deg >= 1 always
}

// ---------------- GEMM: h1 = X[n,128] @ W1[128,128] ----------------

__launch_bounds__(256)
__global__ void gemm_x_w1(const float* __restrict__ X, const float* __restrict__ W,
                          float* __restrict__ C, int n) {
  __shared__ float sW[128 * 128];  // 64 KB
  __shared__ float sX[32 * 128];   // 16 KB
  int row0 = blockIdx.x * 32;
  for (int i = threadIdx.x; i < 128 * 128; i += 256) sW[i] = W[i];
  for (int i = threadIdx.x; i < 32 * 128; i += 256) {
    int r = row0 + (i >> 7);
    sX[i] = (r < n) ? X[(size_t)r * 128 + (i & 127)] : 0.0f;
  }
  __syncthreads();
  int tg = threadIdx.x >> 5;   // 0..7  -> rows tg*4 .. tg*4+3
  int tx = threadIdx.x & 31;   // cols tx*4 .. tx*4+3
  float4 acc[4] = {};
  const float* x0 = sX + (tg * 4) * 128;
  for (int k = 0; k < 128; ++k) {
    float4 wv = *(const float4*)(sW + k * 128 + tx * 4);
#pragma unroll
    for (int r = 0; r < 4; ++r) {
      float xv = x0[r * 128 + k];
      acc[r].x += xv * wv.x; acc[r].y += xv * wv.y;
      acc[r].z += xv * wv.z; acc[r].w += xv * wv.w;
    }
  }
#pragma unroll
  for (int r = 0; r < 4; ++r) {
    int row = row0 + tg * 4 + r;
    if (row < n) *(float4*)(C + (size_t)row * 128 + tx * 4) = acc[r];
  }
}

// ---------------- GEMM: h2 = H[n,128] @ W2[128,40] ----------------

__launch_bounds__(256)
__global__ void gemm_h_w2(const float* __restrict__ H, const float* __restrict__ W2,
                          float* __restrict__ C, int n) {
  __shared__ float sW[128 * 40];  // 20 KB
  __shared__ float sX[64 * 128];  // 32 KB
  int row0 = blockIdx.x * 64;
  for (int i = threadIdx.x; i < 128 * 40; i += 256) sW[i] = W2[i];
  for (int i = threadIdx.x; i < 64 * 128; i += 256) {
    int r = row0 + (i >> 7);
    sX[i] = (r < n) ? H[(size_t)r * 128 + (i & 127)] : 0.0f;
  }
  __syncthreads();
  int cg = threadIdx.x & 7;    // cols cg*5 .. cg*5+4
  int rg = threadIdx.x >> 3;   // 0..31 -> rows rg*2 .. rg*2+1
  float acc[2][5] = {};
  const float* x0 = sX + (rg * 2) * 128;
  for (int k = 0; k < 128; ++k) {
    float xv0 = x0[k], xv1 = x0[128 + k];
    const float* wr = sW + k * 40 + cg * 5;
#pragma unroll
    for (int c = 0; c < 5; ++c) {
      float wv = wr[c];
      acc[0][c] += xv0 * wv;
      acc[1][c] += xv1 * wv;
    }
  }
#pragma unroll
  for (int r = 0; r < 2; ++r) {
    int row = row0 + rg * 2 + r;
    if (row < n) {
      float* out = C + (size_t)row * 40 + cg * 5;
#pragma unroll
      for (int c = 0; c < 5; ++c) out[c] = acc[r][c];
    }
  }
}

// ---------------- aggregation: init with self-loop term ----------------

__global__ void self_loop_init128(const float* __restrict__ h, const float* __restrict__ dinv,
                                  float* __restrict__ acc, int n) {
  size_t total = (size_t)n * 128;
  size_t stride = (size_t)gridDim.x * blockDim.x;
  for (size_t i = (size_t)blockIdx.x * blockDim.x + threadIdx.x; i < total; i += stride) {
    float dv = dinv[i >> 7];
    acc[i] = h[i] * dv * dv;
  }
}

__global__ void self_loop_init40(const float* __restrict__ h, const float* __restrict__ dinv,
                                 float* __restrict__ acc, int n) {
  size_t total = (size_t)n * 40;
  size_t stride = (size_t)gridDim.x * blockDim.x;
  for (size_t i = (size_t)blockIdx.x * blockDim.x + threadIdx.x; i < total; i += stride) {
    float dv = dinv[i / 40];
    acc[i] = h[i] * dv * dv;
  }
}

// ---------------- aggregation: per-edge atomic scatter ----------------

__launch_bounds__(256)
__global__ void scatter128(const int* __restrict__ src, const int* __restrict__ dst,
                           const float* __restrict__ dinv, const float* __restrict__ h,
                           float* __restrict__ acc, int E) {
  int lane = threadIdx.x & 63;
  int wid = blockIdx.x * 4 + (threadIdx.x >> 6);
  int nw = gridDim.x * 4;
  for (int e = wid; e < E; e += nw) {
    int s = src[e], d = dst[e];
    float w = dinv[s] * dinv[d];
    const float* hs = h + (size_t)s * 128;
    float* ad = acc + (size_t)d * 128;
    atomicAdd(ad + lane,      hs[lane] * w);
    atomicAdd(ad + lane + 64, hs[lane + 64] * w);
  }
}

__launch_bounds__(256)
__global__ void scatter40(const int* __restrict__ src, const int* __restrict__ dst,
                          const float* __restrict__ dinv, const float* __restrict__ h2,
                          float* __restrict__ acc, int E) {
  int lane = threadIdx.x & 63;
  int wid = blockIdx.x * 4 + (threadIdx.x >> 6);
  int nw = gridDim.x * 4;
  for (int e = wid; e < E; e += nw) {
    int s = src[e], d = dst[e];
    float w = dinv[s] * dinv[d];
    if (lane < 40)
      atomicAdd(acc + (size_t)d * 40 + lane, h2[(size_t)s * 40 + lane] * w);
  }
}

// ---------------- finalize ----------------

__global__ void finalize_hidden(float* __restrict__ acc, const float* __restrict__ b, int n) {
  size_t total = (size_t)n * 128;
  size_t stride = (size_t)gridDim.x * blockDim.x;
  for (size_t i = (size_t)blockIdx.x * blockDim.x + threadIdx.x; i < total; i += stride) {
    acc[i] = fmaxf(acc[i] + b[i & 127], 0.0f);
  }
}

__global__ void finalize_logits(float* __restrict__ acc, const float* __restrict__ b, int n) {
  size_t total = (size_t)n * 40;
  size_t stride = (size_t)gridDim.x * blockDim.x;
  for (size_t i = (size_t)blockIdx.x * blockDim.x + threadIdx.x; i < total; i += stride) {
    acc[i] = acc[i] + b[i % 40];
  }
}

// ---------------- launch ----------------

extern "C" void kernel_launch(void* const* d_in, const int* in_sizes, int n_in,
                              void* d_out, int out_size, void* d_ws, size_t ws_size,
                              hipStream_t stream) {
  const float* x  = (const float*)d_in[0];
  const int*   ei = (const int*)d_in[1];
  const float* W1 = (const float*)d_in[2];
  const float* b1 = (const float*)d_in[3];
  const float* W2 = (const float*)d_in[4];
  const float* b2 = (const float*)d_in[5];

  int n = in_sizes[0] / 128;   // 100000
  int E = in_sizes[1] / 2;     // 1600000
  const int* src = ei;
  const int* dst = ei + E;

  float* out = (float*)d_out;
  float* logits = out;                    // n*40
  float* hidden = out + (size_t)n * 40;   // n*128

  float* dinv = (float*)d_ws;             // n floats (deg -> dinv in place)
  float* h1   = dinv + 131072;            // n*128 floats
  float* h2   = h1 + (size_t)n * 128;     // n*40  floats

  // degree + normalization
  deg_init<<<(n + 255) / 256, 256, 0, stream>>>(dinv, n);
  deg_count<<<2048, 256, 0, stream>>>(dst, dinv, E);
  deg_to_dinv<<<(n + 255) / 256, 256, 0, stream>>>(dinv, n);

  // layer 1
  gemm_x_w1<<<(n + 31) / 32, 256, 0, stream>>>(x, W1, h1, n);
  self_loop_init128<<<2048, 256, 0, stream>>>(h1, dinv, hidden, n);
  scatter128<<<4096, 256, 0, stream>>>(src, dst, dinv, h1, hidden, E);
  finalize_hidden<<<2048, 256, 0, stream>>>(hidden, b1, n);

  // layer 2
  gemm_h_w2<<<(n + 63) / 64, 256, 0, stream>>>(hidden, W2, h2, n);
  self_loop_init40<<<2048, 256, 0, stream>>>(h2, dinv, logits, n);
  scatter40<<<4096, 256, 0, stream>>>(src, dst, dinv, h2, logits, E);
  finalize_logits<<<2048, 256, 0, stream>>>(logits, b2, n);
}

// Round 2
// 613.094 us; speedup vs baseline: 1.9212x; 1.9212x over previous
//
#include <hip/hip_runtime.h>

// ---------------- zero / degree ----------------

__global__ void zero_int(int* __restrict__ p, int n) {
  int i = blockIdx.x * blockDim.x + threadIdx.x;
  if (i < n) p[i] = 0;
}

__global__ void deg_count_int(const int* __restrict__ dst, int* __restrict__ degi, int E) {
  int i = blockIdx.x * blockDim.x + threadIdx.x;
  int stride = gridDim.x * blockDim.x;
  for (; i < E; i += stride) atomicAdd(&degi[dst[i]], 1);
}

__global__ void dinv_from_deg(const int* __restrict__ degi, float* __restrict__ dinv, int n) {
  int i = blockIdx.x * blockDim.x + threadIdx.x;
  if (i < n) dinv[i] = rsqrtf((float)(degi[i] + 1));  // +1 self-loop
}

// ---------------- exclusive scan (3-kernel, 1024 elems/block) ----------------

__global__ void scan1(const int* __restrict__ degi, int* __restrict__ chunk,
                      int* __restrict__ partials, int n) {
  __shared__ int s[256];
  int t = threadIdx.x;
  int base = blockIdx.x * 1024 + t * 4;
  int v[4];
#pragma unroll
  for (int k = 0; k < 4; ++k) v[k] = (base + k < n) ? degi[base + k] : 0;
  int tsum = v[0] + v[1] + v[2] + v[3];
  s[t] = tsum;
  __syncthreads();
  for (int off = 1; off < 256; off <<= 1) {
    int val = (t >= off) ? s[t - off] : 0;
    __syncthreads();
    s[t] += val;
    __syncthreads();
  }
  int run = s[t] - tsum;  // exclusive
#pragma unroll
  for (int k = 0; k < 4; ++k) {
    if (base + k < n) chunk[base + k] = run;
    run += v[k];
  }
  if (t == 255) partials[blockIdx.x] = s[255];
}

__global__ void scan2(int* __restrict__ partials, int nb) {
  __shared__ int s[256];
  int t = threadIdx.x;
  int v = (t < nb) ? partials[t] : 0;
  s[t] = v;
  __syncthreads();
  for (int off = 1; off < 256; off <<= 1) {
    int val = (t >= off) ? s[t - off] : 0;
    __syncthreads();
    s[t] += val;
    __syncthreads();
  }
  if (t < nb) partials[t] = s[t] - v;  // exclusive
}

__global__ void scan3(int* __restrict__ rowptr, int* __restrict__ cursor,
                      const int* __restrict__ partials, int n, int E) {
  int i = blockIdx.x * blockDim.x + threadIdx.x;
  if (i < n) {
    int v = rowptr[i] + partials[i >> 10];
    rowptr[i] = v;
    cursor[i] = v;
  }
  if (i == n) rowptr[n] = E;
}

// ---------------- CSR fill ----------------

__global__ void csr_fill(const int* __restrict__ src, const int* __restrict__ dst,
                         int* __restrict__ cursor, int* __restrict__ esrc, int E) {
  int i = blockIdx.x * blockDim.x + threadIdx.x;
  int stride = gridDim.x * blockDim.x;
  for (; i < E; i += stride) {
    int d = dst[i];
    int pos = atomicAdd(&cursor[d], 1);
    esrc[pos] = src[i];
  }
}

// ---------------- GEMM: h1 = X[n,128] @ W1[128,128] ----------------

__launch_bounds__(256)
__global__ void gemm_x_w1(const float* __restrict__ X, const float* __restrict__ W,
                          float* __restrict__ C, int n) {
  __shared__ float sW[128 * 128];  // 64 KB
  __shared__ float sX[32 * 128];   // 16 KB
  int row0 = blockIdx.x * 32;
  for (int i = threadIdx.x; i < 128 * 128; i += 256) sW[i] = W[i];
  for (int i = threadIdx.x; i < 32 * 128; i += 256) {
    int r = row0 + (i >> 7);
    sX[i] = (r < n) ? X[(size_t)r * 128 + (i & 127)] : 0.0f;
  }
  __syncthreads();
  int tg = threadIdx.x >> 5;
  int tx = threadIdx.x & 31;
  float4 acc[4] = {};
  const float* x0 = sX + (tg * 4) * 128;
  for (int k = 0; k < 128; ++k) {
    float4 wv = *(const float4*)(sW + k * 128 + tx * 4);
#pragma unroll
    for (int r = 0; r < 4; ++r) {
      float xv = x0[r * 128 + k];
      acc[r].x += xv * wv.x; acc[r].y += xv * wv.y;
      acc[r].z += xv * wv.z; acc[r].w += xv * wv.w;
    }
  }
#pragma unroll
  for (int r = 0; r < 4; ++r) {
    int row = row0 + tg * 4 + r;
    if (row < n) *(float4*)(C + (size_t)row * 128 + tx * 4) = acc[r];
  }
}

// ---------------- GEMM: h2 = H[n,128] @ W2[128,40] ----------------

__launch_bounds__(256)
__global__ void gemm_h_w2(const float* __restrict__ H, const float* __restrict__ W2,
                          float* __restrict__ C, int n) {
  __shared__ float sW[128 * 40];
  __shared__ float sX[64 * 128];
  int row0 = blockIdx.x * 64;
  for (int i = threadIdx.x; i < 128 * 40; i += 256) sW[i] = W2[i];
  for (int i = threadIdx.x; i < 64 * 128; i += 256) {
    int r = row0 + (i >> 7);
    sX[i] = (r < n) ? H[(size_t)r * 128 + (i & 127)] : 0.0f;
  }
  __syncthreads();
  int cg = threadIdx.x & 7;
  int rg = threadIdx.x >> 3;
  float acc[2][5] = {};
  const float* x0 = sX + (rg * 2) * 128;
  for (int k = 0; k < 128; ++k) {
    float xv0 = x0[k], xv1 = x0[128 + k];
    const float* wr = sW + k * 40 + cg * 5;
#pragma unroll
    for (int c = 0; c < 5; ++c) {
      float wv = wr[c];
      acc[0][c] += xv0 * wv;
      acc[1][c] += xv1 * wv;
    }
  }
#pragma unroll
  for (int r = 0; r < 2; ++r) {
    int row = row0 + rg * 2 + r;
    if (row < n) {
      float* out = C + (size_t)row * 40 + cg * 5;
#pragma unroll
      for (int c = 0; c < 5; ++c) out[c] = acc[r][c];
    }
  }
}

// ---------------- gather-aggregate (CSR), fused self-loop + bias (+ReLU) ----------------

// One wave per node; lanes cover 128 cols as float2. out = relu(dinv_d*(sum_s h[s]*dinv_s + h[d]*dinv_d) + b)
__launch_bounds__(256)
__global__ void gather128(const int* __restrict__ rowptr, const int* __restrict__ esrc,
                          const float* __restrict__ dinv, const float* __restrict__ h,
                          const float* __restrict__ b, float* __restrict__ out, int n) {
  int lane = threadIdx.x & 63;
  int node = blockIdx.x * 4 + (threadIdx.x >> 6);
  if (node >= n) return;
  int beg = rowptr[node], end = rowptr[node + 1];
  const float2* H = (const float2*)h;
  float2 g0 = {0.f, 0.f}, g1 = {0.f, 0.f};
  int j = beg;
  for (; j + 1 < end; j += 2) {
    int s0 = esrc[j], s1 = esrc[j + 1];
    float w0 = dinv[s0], w1 = dinv[s1];
    float2 a0 = H[(size_t)s0 * 64 + lane];
    float2 a1 = H[(size_t)s1 * 64 + lane];
    g0.x += a0.x * w0; g0.y += a0.y * w0;
    g1.x += a1.x * w1; g1.y += a1.y * w1;
  }
  if (j < end) {
    int s0 = esrc[j];
    float w0 = dinv[s0];
    float2 a0 = H[(size_t)s0 * 64 + lane];
    g0.x += a0.x * w0; g0.y += a0.y * w0;
  }
  float dd = dinv[node];
  float2 self = H[(size_t)node * 64 + lane];
  float gx = (g0.x + g1.x + self.x * dd) * dd + b[lane * 2];
  float gy = (g0.y + g1.y + self.y * dd) * dd + b[lane * 2 + 1];
  float2 o = {fmaxf(gx, 0.f), fmaxf(gy, 0.f)};
  ((float2*)out)[(size_t)node * 64 + lane] = o;
}

// One wave per node; lanes 0..39 cover the 40 cols. No ReLU.
__launch_bounds__(256)
__global__ void gather40(const int* __restrict__ rowptr, const int* __restrict__ esrc,
                         const float* __restrict__ dinv, const float* __restrict__ h,
                         const float* __restrict__ b, float* __restrict__ out, int n) {
  int lane = threadIdx.x & 63;
  int node = blockIdx.x * 4 + (threadIdx.x >> 6);
  if (node >= n) return;
  bool act = lane < 40;
  int beg = rowptr[node], end = rowptr[node + 1];
  float g0 = 0.f, g1 = 0.f;
  int j = beg;
  for (; j + 1 < end; j += 2) {
    int s0 = esrc[j], s1 = esrc[j + 1];
    float w0 = dinv[s0], w1 = dinv[s1];
    if (act) {
      g0 += h[(size_t)s0 * 40 + lane] * w0;
      g1 += h[(size_t)s1 * 40 + lane] * w1;
    }
  }
  if (j < end) {
    int s0 = esrc[j];
    float w0 = dinv[s0];
    if (act) g0 += h[(size_t)s0 * 40 + lane] * w0;
  }
  if (act) {
    float dd = dinv[node];
    float v = (g0 + g1 + h[(size_t)node * 40 + lane] * dd) * dd + b[lane];
    out[(size_t)node * 40 + lane] = v;
  }
}

// ---------------- launch ----------------

extern "C" void kernel_launch(void* const* d_in, const int* in_sizes, int n_in,
                              void* d_out, int out_size, void* d_ws, size_t ws_size,
                              hipStream_t stream) {
  const float* x  = (const float*)d_in[0];
  const int*   ei = (const int*)d_in[1];
  const float* W1 = (const float*)d_in[2];
  const float* b1 = (const float*)d_in[3];
  const float* W2 = (const float*)d_in[4];
  const float* b2 = (const float*)d_in[5];

  int n = in_sizes[0] / 128;   // 100000
  int E = in_sizes[1] / 2;     // 1600000
  const int* src = ei;
  const int* dst = ei + E;

  float* out = (float*)d_out;
  float* logits = out;                    // n*40
  float* hidden = out + (size_t)n * 40;   // n*128

  // workspace layout (4-byte elements)
  const int PAD = 131072;
  int*   degi     = (int*)d_ws;                 // PAD
  float* dinv     = (float*)d_ws + PAD;         // PAD
  int*   rowptr   = (int*)d_ws + 2 * PAD;       // PAD (n+1 used)
  int*   cursor   = (int*)d_ws + 3 * PAD;       // PAD
  int*   partials = (int*)d_ws + 4 * PAD;       // 1024
  int*   esrc     = (int*)d_ws + 4 * PAD + 1024;        // E
  float* h1       = (float*)d_ws + 4 * PAD + 1024 + E;  // n*128
  float* h2       = h1 + (size_t)n * 128;               // n*40

  int nb = (n + 1023) / 1024;  // scan blocks (98)

  // ---- CSR build ----
  zero_int<<<(n + 255) / 256, 256, 0, stream>>>(degi, n);
  deg_count_int<<<2048, 256, 0, stream>>>(dst, degi, E);
  dinv_from_deg<<<(n + 255) / 256, 256, 0, stream>>>(degi, dinv, n);
  scan1<<<nb, 256, 0, stream>>>(degi, rowptr, partials, n);
  scan2<<<1, 256, 0, stream>>>(partials, nb);
  scan3<<<(n + 256) / 256, 256, 0, stream>>>(rowptr, cursor, partials, n, E);
  csr_fill<<<2048, 256, 0, stream>>>(src, dst, cursor, esrc, E);

  // ---- layer 1 ----
  gemm_x_w1<<<(n + 31) / 32, 256, 0, stream>>>(x, W1, h1, n);
  gather128<<<(n + 3) / 4, 256, 0, stream>>>(rowptr, esrc, dinv, h1, b1, hidden, n);

  // ---- layer 2 ----
  gemm_h_w2<<<(n + 63) / 64, 256, 0, stream>>>(hidden, W2, h2, n);
  gather40<<<(n + 3) / 4, 256, 0, stream>>>(rowptr, esrc, dinv, h2, b2, logits, n);
}

// Round 3
// 525.027 us; speedup vs baseline: 2.2435x; 1.1677x over previous
//
#include <hip/hip_runtime.h>
#include <hip/hip_bf16.h>

typedef unsigned int uint;
typedef unsigned short ushort;

static __device__ __forceinline__ ushort f2b(float f) {
  __hip_bfloat16 h = __float2bfloat16(f);  // RNE
  union { __hip_bfloat16 h; ushort u; } cv; cv.h = h; return cv.u;
}
static __device__ __forceinline__ float blo(uint u) { return __uint_as_float(u << 16); }
static __device__ __forceinline__ float bhi(uint u) { return __uint_as_float(u & 0xffff0000u); }

// ---------------- zero / degree ----------------

__global__ void zero_int(int* __restrict__ p, int n) {
  int i = blockIdx.x * blockDim.x + threadIdx.x;
  if (i < n) p[i] = 0;
}

__global__ void deg_count_int(const int* __restrict__ dst, int* __restrict__ degi, int E) {
  int i = blockIdx.x * blockDim.x + threadIdx.x;
  int stride = gridDim.x * blockDim.x;
  for (; i < E; i += stride) atomicAdd(&degi[dst[i]], 1);
}

__global__ void dinv_from_deg(const int* __restrict__ degi, float* __restrict__ dinv, int n) {
  int i = blockIdx.x * blockDim.x + threadIdx.x;
  if (i < n) dinv[i] = rsqrtf((float)(degi[i] + 1));  // +1 self-loop
}

// ---------------- exclusive scan ----------------

__global__ void scan1(const int* __restrict__ degi, int* __restrict__ chunk,
                      int* __restrict__ partials, int n) {
  __shared__ int s[256];
  int t = threadIdx.x;
  int base = blockIdx.x * 1024 + t * 4;
  int v[4];
#pragma unroll
  for (int k = 0; k < 4; ++k) v[k] = (base + k < n) ? degi[base + k] : 0;
  int tsum = v[0] + v[1] + v[2] + v[3];
  s[t] = tsum;
  __syncthreads();
  for (int off = 1; off < 256; off <<= 1) {
    int val = (t >= off) ? s[t - off] : 0;
    __syncthreads();
    s[t] += val;
    __syncthreads();
  }
  int run = s[t] - tsum;
#pragma unroll
  for (int k = 0; k < 4; ++k) {
    if (base + k < n) chunk[base + k] = run;
    run += v[k];
  }
  if (t == 255) partials[blockIdx.x] = s[255];
}

__global__ void scan2(int* __restrict__ partials, int nb) {
  __shared__ int s[256];
  int t = threadIdx.x;
  int v = (t < nb) ? partials[t] : 0;
  s[t] = v;
  __syncthreads();
  for (int off = 1; off < 256; off <<= 1) {
    int val = (t >= off) ? s[t - off] : 0;
    __syncthreads();
    s[t] += val;
    __syncthreads();
  }
  if (t < nb) partials[t] = s[t] - v;
}

__global__ void scan3(int* __restrict__ rowptr, int* __restrict__ cursor,
                      const int* __restrict__ partials, int n, int E) {
  int i = blockIdx.x * blockDim.x + threadIdx.x;
  if (i < n) {
    int v = rowptr[i] + partials[i >> 10];
    rowptr[i] = v;
    cursor[i] = v;
  }
  if (i == n) rowptr[n] = E;
}

// ---------------- CSR fill ----------------

__global__ void csr_fill(const int* __restrict__ src, const int* __restrict__ dst,
                         int* __restrict__ cursor, int* __restrict__ esrc, int E) {
  int i = blockIdx.x * blockDim.x + threadIdx.x;
  int stride = gridDim.x * blockDim.x;
  for (; i < E; i += stride) {
    int d = dst[i];
    int pos = atomicAdd(&cursor[d], 1);
    esrc[pos] = src[i];
  }
}

// ---------------- GEMM1: h1s[r][c] = bf16( (X@W1)[r][c] * dinv[r] ) ----------------

__launch_bounds__(256)
__global__ void gemm_x_w1(const float* __restrict__ X, const float* __restrict__ W,
                          const float* __restrict__ dinv, ushort* __restrict__ H1S, int n) {
  __shared__ float sW[128 * 128];  // 64 KB
  __shared__ float sX[32 * 128];   // 16 KB
  int row0 = blockIdx.x * 32;
  for (int i = threadIdx.x; i < 128 * 128; i += 256) sW[i] = W[i];
  for (int i = threadIdx.x; i < 32 * 128; i += 256) {
    int r = row0 + (i >> 7);
    sX[i] = (r < n) ? X[(size_t)r * 128 + (i & 127)] : 0.0f;
  }
  __syncthreads();
  int tg = threadIdx.x >> 5;
  int tx = threadIdx.x & 31;
  float4 acc[4] = {};
  const float* x0 = sX + (tg * 4) * 128;
  for (int k = 0; k < 128; ++k) {
    float4 wv = *(const float4*)(sW + k * 128 + tx * 4);
#pragma unroll
    for (int r = 0; r < 4; ++r) {
      float xv = x0[r * 128 + k];
      acc[r].x += xv * wv.x; acc[r].y += xv * wv.y;
      acc[r].z += xv * wv.z; acc[r].w += xv * wv.w;
    }
  }
#pragma unroll
  for (int r = 0; r < 4; ++r) {
    int row = row0 + tg * 4 + r;
    if (row < n) {
      float dv = dinv[row];
      uint2 p;
      p.x = (uint)f2b(acc[r].x * dv) | ((uint)f2b(acc[r].y * dv) << 16);
      p.y = (uint)f2b(acc[r].z * dv) | ((uint)f2b(acc[r].w * dv) << 16);
      *(uint2*)(H1S + (size_t)row * 128 + tx * 4) = p;
    }
  }
}

// ---------------- GEMM2: h2s[r][c] = bf16( (Hb@W2)[r][c] * dinv[r] ) ----------------

__launch_bounds__(256)
__global__ void gemm_h_w2(const ushort* __restrict__ Hb, const float* __restrict__ W2,
                          const float* __restrict__ dinv, ushort* __restrict__ H2S, int n) {
  __shared__ float sW[128 * 40];  // 20 KB
  __shared__ float sX[64 * 128];  // 32 KB
  int row0 = blockIdx.x * 64;
  for (int i = threadIdx.x; i < 128 * 40; i += 256) sW[i] = W2[i];
  for (int i = threadIdx.x; i < 64 * 128; i += 256) {
    int r = row0 + (i >> 7);
    sX[i] = (r < n) ? __uint_as_float((uint)Hb[(size_t)r * 128 + (i & 127)] << 16) : 0.0f;
  }
  __syncthreads();
  int cg = threadIdx.x & 7;
  int rg = threadIdx.x >> 3;
  float acc[2][5] = {};
  const float* x0 = sX + (rg * 2) * 128;
  for (int k = 0; k < 128; ++k) {
    float xv0 = x0[k], xv1 = x0[128 + k];
    const float* wr = sW + k * 40 + cg * 5;
#pragma unroll
    for (int c = 0; c < 5; ++c) {
      float wv = wr[c];
      acc[0][c] += xv0 * wv;
      acc[1][c] += xv1 * wv;
    }
  }
#pragma unroll
  for (int r = 0; r < 2; ++r) {
    int row = row0 + rg * 2 + r;
    if (row < n) {
      float dv = dinv[row];
      ushort* out = H2S + (size_t)row * 40 + cg * 5;
#pragma unroll
      for (int c = 0; c < 5; ++c) out[c] = f2b(acc[r][c] * dv);
    }
  }
}

// ---------------- gather 128-wide (bf16 rows, prescaled) ----------------
// hidden = relu(dinv_d*(sum_{s in N(d)} h1s[s] + h1s[d]) + b1); also emit bf16 copy.

__launch_bounds__(256)
__global__ void gather128(const int* __restrict__ rowptr, const int* __restrict__ esrc,
                          const float* __restrict__ dinv, const uint* __restrict__ H,
                          const float* __restrict__ b, float* __restrict__ out,
                          uint* __restrict__ outb, int n) {
  int lane = threadIdx.x & 63;
  int node = blockIdx.x * 4 + (threadIdx.x >> 6);
  if (node >= n) return;
  int beg = rowptr[node], end = rowptr[node + 1];
  float gx0 = 0.f, gy0 = 0.f, gx1 = 0.f, gy1 = 0.f;
  int j = beg;
  for (; j + 1 < end; j += 2) {
    int s0 = esrc[j], s1 = esrc[j + 1];
    uint u0 = H[(size_t)s0 * 64 + lane];
    uint u1 = H[(size_t)s1 * 64 + lane];
    gx0 += blo(u0); gy0 += bhi(u0);
    gx1 += blo(u1); gy1 += bhi(u1);
  }
  if (j < end) {
    uint u0 = H[(size_t)esrc[j] * 64 + lane];
    gx0 += blo(u0); gy0 += bhi(u0);
  }
  uint us = H[(size_t)node * 64 + lane];
  float dd = dinv[node];
  float2 bb = ((const float2*)b)[lane];
  float ox = fmaxf((gx0 + gx1 + blo(us)) * dd + bb.x, 0.f);
  float oy = fmaxf((gy0 + gy1 + bhi(us)) * dd + bb.y, 0.f);
  float2 o = {ox, oy};
  ((float2*)out)[(size_t)node * 64 + lane] = o;
  outb[(size_t)node * 64 + lane] = (uint)f2b(ox) | ((uint)f2b(oy) << 16);
}

// ---------------- gather 40-wide (bf16 rows, prescaled) ----------------
// 3 edges per wave: lanes 0-59 in three 20-lane groups; shuffle-reduce at end.

__launch_bounds__(256)
__global__ void gather40(const int* __restrict__ rowptr, const int* __restrict__ esrc,
                         const float* __restrict__ dinv, const uint* __restrict__ H2,
                         const float* __restrict__ b, float* __restrict__ out, int n) {
  int lane = threadIdx.x & 63;
  int node = blockIdx.x * 4 + (threadIdx.x >> 6);
  if (node >= n) return;
  int es = lane / 20;        // edge slot 0..2 (lane 60-63 -> 3, inactive)
  int c = lane % 20;         // dword column
  bool act = lane < 60;
  int beg = rowptr[node], end = rowptr[node + 1];
  float gx = 0.f, gy = 0.f;
  int j = beg;
  for (; j + 3 <= end; j += 3) {
    if (act) {
      int s = esrc[j + es];
      uint u = H2[(size_t)s * 20 + c];
      gx += blo(u); gy += bhi(u);
    }
  }
  int rem = end - j;
  if (act && es < rem) {
    int s = esrc[j + es];
    uint u = H2[(size_t)s * 20 + c];
    gx += blo(u); gy += bhi(u);
  }
  // reduce three 20-lane groups onto lanes 0..19
  float tx = gx + __shfl(gx, c + 20) + __shfl(gx, c + 40);
  float ty = gy + __shfl(gy, c + 20) + __shfl(gy, c + 40);
  if (lane < 20) {
    uint us = H2[(size_t)node * 20 + c];
    float dd = dinv[node];
    float2 bb = ((const float2*)b)[c];
    float2 o = {(tx + blo(us)) * dd + bb.x, (ty + bhi(us)) * dd + bb.y};
    ((float2*)out)[(size_t)node * 20 + c] = o;
  }
}

// ---------------- launch ----------------

extern "C" void kernel_launch(void* const* d_in, const int* in_sizes, int n_in,
                              void* d_out, int out_size, void* d_ws, size_t ws_size,
                              hipStream_t stream) {
  const float* x  = (const float*)d_in[0];
  const int*   ei = (const int*)d_in[1];
  const float* W1 = (const float*)d_in[2];
  const float* b1 = (const float*)d_in[3];
  const float* W2 = (const float*)d_in[4];
  const float* b2 = (const float*)d_in[5];

  int n = in_sizes[0] / 128;   // 100000
  int E = in_sizes[1] / 2;     // 1600000
  const int* src = ei;
  const int* dst = ei + E;

  float* out = (float*)d_out;
  float* logits = out;                    // n*40
  float* hidden = out + (size_t)n * 40;   // n*128

  // workspace layout (4-byte units unless noted)
  const int PAD = 131072;
  int*    degi     = (int*)d_ws;
  float*  dinv     = (float*)d_ws + PAD;
  int*    rowptr   = (int*)d_ws + 2 * PAD;
  int*    cursor   = (int*)d_ws + 3 * PAD;
  int*    partials = (int*)d_ws + 4 * PAD;              // 1024
  int*    esrc     = (int*)d_ws + 4 * PAD + 1024;       // E
  ushort* h1s      = (ushort*)((int*)d_ws + 4 * PAD + 1024 + E);  // n*128 bf16
  ushort* hb       = h1s + (size_t)n * 128;                        // n*128 bf16
  ushort* h2s      = hb + (size_t)n * 128;                         // n*40 bf16

  int nb = (n + 1023) / 1024;

  // ---- CSR build + dinv ----
  zero_int<<<(n + 255) / 256, 256, 0, stream>>>(degi, n);
  deg_count_int<<<2048, 256, 0, stream>>>(dst, degi, E);
  dinv_from_deg<<<(n + 255) / 256, 256, 0, stream>>>(degi, dinv, n);
  scan1<<<nb, 256, 0, stream>>>(degi, rowptr, partials, n);
  scan2<<<1, 256, 0, stream>>>(partials, nb);
  scan3<<<(n + 256) / 256, 256, 0, stream>>>(rowptr, cursor, partials, n, E);
  csr_fill<<<2048, 256, 0, stream>>>(src, dst, cursor, esrc, E);

  // ---- layer 1 ----
  gemm_x_w1<<<(n + 31) / 32, 256, 0, stream>>>(x, W1, dinv, h1s, n);
  gather128<<<(n + 3) / 4, 256, 0, stream>>>(rowptr, esrc, dinv, (const uint*)h1s, b1,
                                             hidden, (uint*)hb, n);

  // ---- layer 2 ----
  gemm_h_w2<<<(n + 63) / 64, 256, 0, stream>>>(hb, W2, dinv, h2s, n);
  gather40<<<(n + 3) / 4, 256, 0, stream>>>(rowptr, esrc, dinv, (const uint*)h2s, b2,
                                            logits, n);
}